// Round 1
// baseline (440.080 us; speedup 1.0000x reference)
//
#include <hip/hip_runtime.h>

#define B_ROWS 32768
#define DIN 784
#define D_DIM 256
#define T_TILES 16
#define C_DIM 64
#define BM 32
#define BK 16
#define NTHREADS 256

// Reused LDS region: phase1 (Wp 16384 + x^T 2304), phase2 (sig 16640), phase3 (Wc chunk 34816)
#define SMEM_BYTES 34816

__global__ __launch_bounds__(NTHREADS)
void trix_fused(const float* __restrict__ x, const float* __restrict__ Wp,
                const float* __restrict__ bp, const float* __restrict__ sigs_raw,
                const float* __restrict__ Wc, const float* __restrict__ bc,
                float* __restrict__ out) {
    __shared__ __align__(16) char smem_raw[SMEM_BYTES];
    __shared__ __align__(16) float h_s[BM][260];     // pad: stride%32==4 -> bank spread, rows 16B aligned
    __shared__ int tidx_s[BM];
    __shared__ int counts_s[T_TILES];
    __shared__ int starts_s[T_TILES + 1];
    __shared__ int rows_sorted_s[BM];

    const int tid  = threadIdx.x;
    const int row0 = blockIdx.x * BM;

    // ---------------- Phase 1: h = x @ Wp + bp (f32 VALU tiled GEMM) ----------------
    float (*wp_s)[D_DIM] = (float (*)[D_DIM])smem_raw;            // [16][256]
    float (*xs_t)[36]    = (float (*)[36])(smem_raw + 16384);     // [16][36] transposed x tile

    float4 acc[8];
    #pragma unroll
    for (int m = 0; m < 8; ++m) acc[m] = make_float4(0.f, 0.f, 0.f, 0.f);

    const int cg4 = (tid & 63) * 4;   // 4 output cols
    const int rg8 = (tid >> 6) * 8;   // 8 output rows

    for (int k0 = 0; k0 < DIN; k0 += BK) {
        // stage x tile (transposed): 32 rows x 16 k
        {
            const int m  = tid >> 3;          // 0..31
            const int kb = (tid & 7) * 2;     // 0,2,..,14
            const float2 v = *(const float2*)&x[(size_t)(row0 + m) * DIN + k0 + kb];
            xs_t[kb][m]     = v.x;
            xs_t[kb + 1][m] = v.y;
        }
        // stage Wp tile: 16 k x 256 cols
        #pragma unroll
        for (int i = 0; i < 4; ++i) {
            const int e  = i * NTHREADS + tid;       // 0..1023
            const int kk = e >> 6;
            const int c4 = (e & 63) * 4;
            *(float4*)&wp_s[kk][c4] = *(const float4*)&Wp[(size_t)(k0 + kk) * D_DIM + c4];
        }
        __syncthreads();
        #pragma unroll
        for (int kk = 0; kk < BK; ++kk) {
            const float4 w  = *(const float4*)&wp_s[kk][cg4];
            const float4 xa = *(const float4*)&xs_t[kk][rg8];
            const float4 xb = *(const float4*)&xs_t[kk][rg8 + 4];
            acc[0].x += xa.x * w.x; acc[0].y += xa.x * w.y; acc[0].z += xa.x * w.z; acc[0].w += xa.x * w.w;
            acc[1].x += xa.y * w.x; acc[1].y += xa.y * w.y; acc[1].z += xa.y * w.z; acc[1].w += xa.y * w.w;
            acc[2].x += xa.z * w.x; acc[2].y += xa.z * w.y; acc[2].z += xa.z * w.z; acc[2].w += xa.z * w.w;
            acc[3].x += xa.w * w.x; acc[3].y += xa.w * w.y; acc[3].z += xa.w * w.z; acc[3].w += xa.w * w.w;
            acc[4].x += xb.x * w.x; acc[4].y += xb.x * w.y; acc[4].z += xb.x * w.z; acc[4].w += xb.x * w.w;
            acc[5].x += xb.y * w.x; acc[5].y += xb.y * w.y; acc[5].z += xb.y * w.z; acc[5].w += xb.y * w.w;
            acc[6].x += xb.z * w.x; acc[6].y += xb.z * w.y; acc[6].z += xb.z * w.z; acc[6].w += xb.z * w.w;
            acc[7].x += xb.w * w.x; acc[7].y += xb.w * w.y; acc[7].z += xb.w * w.z; acc[7].w += xb.w * w.w;
        }
        __syncthreads();
    }

    // bias + write h to LDS
    {
        const float4 bpv = *(const float4*)&bp[cg4];
        #pragma unroll
        for (int m = 0; m < 8; ++m) {
            h_s[rg8 + m][cg4 + 0] = acc[m].x + bpv.x;
            h_s[rg8 + m][cg4 + 1] = acc[m].y + bpv.y;
            h_s[rg8 + m][cg4 + 2] = acc[m].z + bpv.z;
            h_s[rg8 + m][cg4 + 3] = acc[m].w + bpv.w;
        }
    }

    // stage ternary-quantized sigs (f64 threshold compare to match np semantics)
    float (*sig_s)[260] = (float (*)[260])smem_raw;   // [16][260]
    #pragma unroll
    for (int i = 0; i < 16; ++i) {
        const int e  = i * NTHREADS + tid;   // 0..4095
        const int tt = e >> 8;
        const int d  = e & 255;
        const double v = (double)sigs_raw[tt * D_DIM + d];
        sig_s[tt][d] = (v > 0.3) ? 1.f : ((v < -0.3) ? -1.f : 0.f);
    }
    __syncthreads();

    // ---------------- Phase 2: scores (f64) + argmax ----------------
    {
        const int r  = tid >> 4;    // 0..15 (also handles r+16)
        const int tt = tid & 15;    // tile
        const float4* h1 = (const float4*)&h_s[r][0];
        const float4* h2 = (const float4*)&h_s[r + 16][0];
        const float4* sg = (const float4*)&sig_s[tt][0];
        double s1 = 0.0, s2 = 0.0;
        for (int d4 = 0; d4 < 64; ++d4) {
            const float4 sv = sg[d4];
            const float4 a  = h1[d4];
            const float4 b  = h2[d4];
            s1 += (double)a.x * (double)sv.x + (double)a.y * (double)sv.y
                + (double)a.z * (double)sv.z + (double)a.w * (double)sv.w;
            s2 += (double)b.x * (double)sv.x + (double)b.y * (double)sv.y
                + (double)b.z * (double)sv.z + (double)b.w * (double)sv.w;
        }
        int i1 = tt, i2 = tt;
        #pragma unroll
        for (int m = 8; m >= 1; m >>= 1) {
            const double o1 = __shfl_xor(s1, m); const int oi1 = __shfl_xor(i1, m);
            if (o1 > s1 || (o1 == s1 && oi1 < i1)) { s1 = o1; i1 = oi1; }
            const double o2 = __shfl_xor(s2, m); const int oi2 = __shfl_xor(i2, m);
            if (o2 > s2 || (o2 == s2 && oi2 < i2)) { s2 = o2; i2 = oi2; }
        }
        if (tt == 0) {
            tidx_s[r]      = i1;
            tidx_s[r + 16] = i2;
            out[(size_t)B_ROWS * C_DIM + row0 + r]      = (float)i1;
            out[(size_t)B_ROWS * C_DIM + row0 + r + 16] = (float)i2;
        }
    }
    __syncthreads();

    // group rows by routed tile
    if (tid < T_TILES) {
        int c = 0;
        for (int r = 0; r < BM; ++r) if (tidx_s[r] == tid) ++c;
        counts_s[tid] = c;
    }
    __syncthreads();
    if (tid == 0) {
        int a = 0;
        for (int t = 0; t < T_TILES; ++t) { starts_s[t] = a; a += counts_s[t]; }
        starts_s[T_TILES] = a;
    }
    __syncthreads();
    if (tid < T_TILES) {
        int pos = starts_s[tid];
        for (int r = 0; r < BM; ++r) if (tidx_s[r] == tid) rows_sorted_s[pos++] = r;
    }
    __syncthreads();

    // ---------------- Phase 3: routed logits = h @ Wc[t] + bc[t] ----------------
    float (*wc_s)[68] = (float (*)[68])smem_raw;   // [128][68] = 34816 B
    const int c  = tid & 63;
    const int ig = tid >> 6;

    for (int t = 0; t < T_TILES; ++t) {
        const int base = starts_s[t];
        const int cnt  = starts_s[t + 1] - base;
        if (cnt == 0) continue;                     // uniform branch

        int   rL[8];
        float accL[8];
        const float bcv = bc[t * C_DIM + c];
        #pragma unroll
        for (int ii = 0; ii < 8; ++ii) {
            const int i = ig + ii * 4;
            rL[ii]   = (i < cnt) ? rows_sorted_s[base + i] : -1;
            accL[ii] = bcv;
        }

        for (int ch = 0; ch < 2; ++ch) {
            const int d0 = ch * 128;
            __syncthreads();   // WAR: previous users of wc_s/sig region done
            #pragma unroll
            for (int i = 0; i < 8; ++i) {
                const int e  = i * NTHREADS + tid;   // 0..2047
                const int dd = e >> 4;
                const int c4 = (e & 15) * 4;
                *(float4*)&wc_s[dd][c4] =
                    *(const float4*)&Wc[(size_t)(t * D_DIM + d0 + dd) * C_DIM + c4];
            }
            __syncthreads();
            #pragma unroll
            for (int ii = 0; ii < 8; ++ii) {
                if (rL[ii] < 0) continue;
                float a = accL[ii];
                const float* hr = &h_s[rL[ii]][d0];
                for (int dd = 0; dd < 128; ++dd) a += hr[dd] * wc_s[dd][c];
                accL[ii] = a;
            }
        }
        #pragma unroll
        for (int ii = 0; ii < 8; ++ii)
            if (rL[ii] >= 0) out[(size_t)(row0 + rL[ii]) * C_DIM + c] = accL[ii];
    }
}

extern "C" void kernel_launch(void* const* d_in, const int* in_sizes, int n_in,
                              void* d_out, int out_size, void* d_ws, size_t ws_size,
                              hipStream_t stream) {
    const float* x    = (const float*)d_in[0];
    const float* Wp   = (const float*)d_in[1];
    const float* bp   = (const float*)d_in[2];
    const float* sigs = (const float*)d_in[3];
    const float* Wc   = (const float*)d_in[4];
    const float* bc   = (const float*)d_in[5];
    float* out = (float*)d_out;
    trix_fused<<<dim3(B_ROWS / BM), dim3(NTHREADS), 0, stream>>>(x, Wp, sigs ? bp : bp, sigs, Wc, bc, out);
}

// Round 2
// 283.431 us; speedup vs baseline: 1.5527x; 1.5527x over previous
//
#include <hip/hip_runtime.h>

typedef short short8 __attribute__((ext_vector_type(8)));
typedef float f32x4 __attribute__((ext_vector_type(4)));

#define B_ROWS 32768
#define DIN 784
#define D_DIM 256
#define T_TILES 16
#define C_DIM 64
#define BM 128
#define NCHUNK 25   // ceil(784/32)

// ---- ws layout (bytes) ----
#define WPT_OFF    0u          // bf16 [25][256][32]  = 409600
#define WCT_OFF    409600u     // bf16 [16][64][256]  = 524288
#define WS_OFF     933888u     // f64  [784][16]      = 100352
#define BS_OFF     1034240u    // f64  [16]           = 128
#define H_OFF      1034368u    // bf16 [32768][256]   = 16777216
#define BUCKET_OFF 17811584u   // i32  [16][32768]    = 2097152
#define CNT_OFF    19908736u   // i32  [16]

static __device__ inline unsigned short f2bf(float f) {
    unsigned u = __builtin_bit_cast(unsigned, f);
    u += 0x7fffu + ((u >> 16) & 1u);          // RNE
    return (unsigned short)(u >> 16);
}
static __device__ inline double qtern(float s) {
    double v = (double)s;
    return (v > 0.3) ? 1.0 : ((v < -0.3) ? -1.0 : 0.0);
}

// ================= prep: WpT chunks (bf16), WcT (bf16), Ws/bs (f64) =========
__global__ __launch_bounds__(256)
void prep_kernel(const float* __restrict__ Wp, const float* __restrict__ bp,
                 const float* __restrict__ sigs_raw, const float* __restrict__ Wc,
                 char* __restrict__ ws) {
    const int bid = blockIdx.x, tid = threadIdx.x;
    unsigned short* wpt = (unsigned short*)(ws + WPT_OFF);
    unsigned short* wct = (unsigned short*)(ws + WCT_OFF);
    double* Wsd = (double*)(ws + WS_OFF);
    double* bsd = (double*)(ws + BS_OFF);

    if (bid < 800) {                       // WpT chunked: [k>>5][col][k&31], zero-pad k>=784
        const int k = bid;
        const float v = (k < DIN) ? Wp[(size_t)k * D_DIM + tid] : 0.f;
        wpt[(k >> 5) * 8192 + tid * 32 + (k & 31)] = f2bf(v);
    } else if (bid < 1584) {               // Ws[k][t] in f64
        const int k = bid - 800;
        const int t = tid >> 4, l = tid & 15;
        double s = 0.0;
        for (int j = 0; j < 16; ++j) {
            const int d = l + 16 * j;
            s += (double)Wp[(size_t)k * D_DIM + d] * qtern(sigs_raw[t * D_DIM + d]);
        }
        #pragma unroll
        for (int m = 8; m >= 1; m >>= 1) s += __shfl_xor(s, m);
        if (l == 0) Wsd[k * 16 + t] = s;
    } else if (bid < 1600) {               // WcT[t][c][d] bf16
        const int t = bid - 1584;
        const int c4 = (tid & 15) * 4, dg = (tid >> 4) * 16;
        for (int j = 0; j < 16; ++j) {
            const int d = dg + j;
            const float4 v = *(const float4*)&Wc[((size_t)t * D_DIM + d) * C_DIM + c4];
            wct[t * 16384 + (c4 + 0) * 256 + d] = f2bf(v.x);
            wct[t * 16384 + (c4 + 1) * 256 + d] = f2bf(v.y);
            wct[t * 16384 + (c4 + 2) * 256 + d] = f2bf(v.z);
            wct[t * 16384 + (c4 + 3) * 256 + d] = f2bf(v.w);
        }
    } else {                               // bs[t] = bp @ sig_t
        if (tid < 16) {
            double s = 0.0;
            for (int d = 0; d < D_DIM; ++d)
                s += (double)bp[d] * qtern(sigs_raw[tid * D_DIM + d]);
            bsd[tid] = s;
        }
    }
}

// ====== G: h = x@Wp+bp (bf16 MFMA) -> ws ; f64 scores = x@Ws+bs ; argmax; bucket
__global__ __launch_bounds__(256, 2)
void gemm_score_kernel(const float* __restrict__ x, const float* __restrict__ bp,
                       char* __restrict__ ws, float* __restrict__ out) {
    __shared__ __align__(16) char u[61440];
    __shared__ int tidx_s[BM];

    unsigned short* Abuf = (unsigned short*)u;               // [2][128*40] bf16
    unsigned short* Bbuf = (unsigned short*)(u + 20480);     // [2][256*40] bf16
    const unsigned short* wpt = (const unsigned short*)(ws + WPT_OFF);
    unsigned short* hbf = (unsigned short*)(ws + H_OFF);
    const double* Wsd = (const double*)(ws + WS_OFF);
    const double* bsd = (const double*)(ws + BS_OFF);
    int* bucket = (int*)(ws + BUCKET_OFF);
    int* cnt = (int*)(ws + CNT_OFF);

    const int tid = threadIdx.x;
    const int row0 = blockIdx.x * BM;
    const int wid = tid >> 6, lane = tid & 63;
    const int wr = wid >> 1, wcid = wid & 1;
    const int lrow = lane & 15, kb8 = (lane >> 4) * 8;
    const int ar = tid >> 1, ako = (tid & 1) * 16;   // A staging: row, k-offset

    f32x4 acc[4][8];
    #pragma unroll
    for (int i = 0; i < 4; ++i)
        #pragma unroll
        for (int j = 0; j < 8; ++j) acc[i][j] = (f32x4){0.f, 0.f, 0.f, 0.f};

    float4 va[4], vb[4];
    // ---- prologue: load+write chunk 0 ----
    {
        const bool valid = ako < DIN;   // always true for c=0
        const float4* p = (const float4*)&x[(size_t)(row0 + ar) * DIN + ako];
        va[0] = p[0]; va[1] = p[1]; va[2] = p[2]; va[3] = p[3];
        (void)valid;
        const float4* q = (const float4*)(wpt + 0 * 8192 + tid * 32);
        vb[0] = q[0]; vb[1] = q[1]; vb[2] = q[2]; vb[3] = q[3];
        unsigned short tmp[16];
        const float* f = (const float*)va;
        #pragma unroll
        for (int i = 0; i < 16; ++i) tmp[i] = f2bf(f[i]);
        unsigned short* da = Abuf + ar * 40 + ako;
        *(short8*)da = *(short8*)tmp; *(short8*)(da + 8) = *(short8*)(tmp + 8);
        unsigned short* db = Bbuf + tid * 40;
        *(float4*)db = vb[0]; *(float4*)(db + 8) = vb[1];
        *(float4*)(db + 16) = vb[2]; *(float4*)(db + 24) = vb[3];
    }
    __syncthreads();

    for (int c = 0; c < NCHUNK; ++c) {
        const int cur = c & 1;
        if (c + 1 < NCHUNK) {           // issue next-chunk global loads early
            const int kbase = (c + 1) * 32 + ako;
            if (kbase < DIN) {
                const float4* p = (const float4*)&x[(size_t)(row0 + ar) * DIN + kbase];
                va[0] = p[0]; va[1] = p[1]; va[2] = p[2]; va[3] = p[3];
            } else {
                va[0] = va[1] = va[2] = va[3] = make_float4(0, 0, 0, 0);
            }
            const float4* q = (const float4*)(wpt + (c + 1) * 8192 + tid * 32);
            vb[0] = q[0]; vb[1] = q[1]; vb[2] = q[2]; vb[3] = q[3];
        }
        // ---- MFMA on buf[cur] ----
        {
            const unsigned short* Ab = Abuf + cur * 5120;
            const unsigned short* Bb = Bbuf + cur * 10240;
            short8 af[4];
            #pragma unroll
            for (int rf = 0; rf < 4; ++rf)
                af[rf] = *(const short8*)(Ab + (wr * 64 + rf * 16 + lrow) * 40 + kb8);
            #pragma unroll
            for (int cf = 0; cf < 8; ++cf) {
                const short8 bfr = *(const short8*)(Bb + (wcid * 128 + cf * 16 + lrow) * 40 + kb8);
                #pragma unroll
                for (int rf = 0; rf < 4; ++rf)
                    acc[rf][cf] = __builtin_amdgcn_mfma_f32_16x16x32_bf16(af[rf], bfr, acc[rf][cf], 0, 0, 0);
            }
        }
        if (c + 1 < NCHUNK) {           // write staged regs into the other buffer
            unsigned short tmp[16];
            const float* f = (const float*)va;
            #pragma unroll
            for (int i = 0; i < 16; ++i) tmp[i] = f2bf(f[i]);
            unsigned short* da = Abuf + (cur ^ 1) * 5120 + ar * 40 + ako;
            *(short8*)da = *(short8*)tmp; *(short8*)(da + 8) = *(short8*)(tmp + 8);
            unsigned short* db = Bbuf + (cur ^ 1) * 10240 + tid * 40;
            *(float4*)db = vb[0]; *(float4*)(db + 8) = vb[1];
            *(float4*)(db + 16) = vb[2]; *(float4*)(db + 24) = vb[3];
        }
        __syncthreads();
    }

    // ---- epilogue: h = acc + bp -> bf16 global (C/D map: col=lane&15, row=(lane>>4)*4+reg)
    #pragma unroll
    for (int cf = 0; cf < 8; ++cf) {
        const int gc = wcid * 128 + cf * 16 + lrow;
        const float bpv = bp[gc];
        #pragma unroll
        for (int rf = 0; rf < 4; ++rf) {
            const int grow = row0 + wr * 64 + rf * 16 + (lane >> 4) * 4;
            #pragma unroll
            for (int r = 0; r < 4; ++r)
                hbf[(size_t)(grow + r) * D_DIM + gc] = f2bf(acc[rf][cf][r] + bpv);
        }
    }

    // ---- score phase: f64 scores = x @ Ws + bs ----
    float*  xs  = (float*)u;               // [128][68]
    double* wss = (double*)(u + 34816);     // [64][16]
    double* scs = (double*)(u + 43008);     // [128][18]

    const int sr = tid >> 1, stg = tid & 1, skh = (tid & 1) * 32;
    double accd[8];
    #pragma unroll
    for (int j = 0; j < 8; ++j) accd[j] = bsd[stg * 8 + j];

    for (int c = 0; c < 13; ++c) {
        __syncthreads();
        #pragma unroll
        for (int i = 0; i < 8; ++i) {
            const int k = c * 64 + skh + i * 4;
            float4 v = (k + 4 <= DIN) ? *(const float4*)&x[(size_t)(row0 + sr) * DIN + k]
                                      : make_float4(0, 0, 0, 0);
            *(float4*)&xs[sr * 68 + skh + i * 4] = v;
        }
        {
            const int k = tid >> 2, tq = (tid & 3) * 4;
            const int gk = c * 64 + k;
            double2 w0, w1;
            if (gk < DIN) {
                w0 = *(const double2*)&Wsd[gk * 16 + tq];
                w1 = *(const double2*)&Wsd[gk * 16 + tq + 2];
            } else { w0.x = w0.y = w1.x = w1.y = 0.0; }
            *(double2*)&wss[k * 16 + tq] = w0;
            *(double2*)&wss[k * 16 + tq + 2] = w1;
        }
        __syncthreads();
        #pragma unroll 4
        for (int k = 0; k < 64; ++k) {
            const double xv = (double)xs[sr * 68 + k];
            const double* wrow = &wss[k * 16 + stg * 8];
            #pragma unroll
            for (int j = 0; j < 8; ++j) accd[j] += xv * wrow[j];
        }
    }
    __syncthreads();
    #pragma unroll
    for (int j = 0; j < 8; ++j) scs[sr * 18 + stg * 8 + j] = accd[j];
    __syncthreads();

    if (tid < BM) {
        const double* s = &scs[tid * 18];
        double best = s[0]; int bi = 0;
        #pragma unroll
        for (int t = 1; t < 16; ++t)
            if (s[t] > best) { best = s[t]; bi = t; }
        tidx_s[tid] = bi;
        out[(size_t)B_ROWS * C_DIM + row0 + tid] = (float)bi;
    }
    __syncthreads();
    if (tid < T_TILES) {
        int c = 0;
        for (int r = 0; r < BM; ++r) c += (tidx_s[r] == tid);
        int pos = atomicAdd(&cnt[tid], c);
        for (int r = 0; r < BM; ++r)
            if (tidx_s[r] == tid) bucket[tid * B_ROWS + (pos++)] = row0 + r;
    }
}

// ====== L: per-tile logits = h[rows] @ Wc[t] + bc[t] via MFMA ===============
__global__ __launch_bounds__(256)
void logits_kernel(const float* __restrict__ bc, const char* __restrict__ ws,
                   float* __restrict__ out) {
    __shared__ __align__(16) unsigned short As[128 * 72];
    __shared__ __align__(16) unsigned short Bs[64 * 72];
    __shared__ int rows_s[128];

    const int tid = threadIdx.x;
    const int t = blockIdx.x >> 8;
    const int c0 = (blockIdx.x & 255) * 128;
    const int* cnt = (const int*)(ws + CNT_OFF);
    const int cntv = cnt[t];
    if (c0 >= cntv) return;

    const int* bucket = (const int*)(ws + BUCKET_OFF);
    const unsigned short* hbf = (const unsigned short*)(ws + H_OFF);
    const unsigned short* wct = (const unsigned short*)(ws + WCT_OFF);

    if (tid < 128) {
        int i = c0 + tid; if (i >= cntv) i = cntv - 1;
        rows_s[tid] = bucket[t * B_ROWS + i];
    }
    __syncthreads();

    const int wid = tid >> 6, lane = tid & 63;
    const int wr = wid >> 1, wcid = wid & 1;
    const int lrow = lane & 15, kb8 = (lane >> 4) * 8;
    const int ar = tid >> 1, akh = (tid & 1) * 32;

    f32x4 acc[4][2];
    #pragma unroll
    for (int i = 0; i < 4; ++i) { acc[i][0] = (f32x4){0,0,0,0}; acc[i][1] = (f32x4){0,0,0,0}; }

    for (int ch = 0; ch < 4; ++ch) {
        {
            const float4* p = (const float4*)&hbf[(size_t)rows_s[ar] * D_DIM + ch * 64 + akh];
            const float4 v0 = p[0], v1 = p[1], v2 = p[2], v3 = p[3];
            unsigned short* dst = As + ar * 72 + akh;
            *(float4*)dst = v0; *(float4*)(dst + 8) = v1;
            *(float4*)(dst + 16) = v2; *(float4*)(dst + 24) = v3;
        }
        if (tid < 128) {
            const int cc = tid >> 1, ckh = (tid & 1) * 32;
            const float4* p = (const float4*)&wct[t * 16384 + cc * 256 + ch * 64 + ckh];
            const float4 v0 = p[0], v1 = p[1], v2 = p[2], v3 = p[3];
            unsigned short* dst = Bs + cc * 72 + ckh;
            *(float4*)dst = v0; *(float4*)(dst + 8) = v1;
            *(float4*)(dst + 16) = v2; *(float4*)(dst + 24) = v3;
        }
        __syncthreads();
        #pragma unroll
        for (int ks = 0; ks < 2; ++ks) {
            const int kb = ks * 32 + kb8;
            short8 bf0 = *(const short8*)(Bs + (wcid * 32 + 0 * 16 + lrow) * 72 + kb);
            short8 bf1 = *(const short8*)(Bs + (wcid * 32 + 1 * 16 + lrow) * 72 + kb);
            #pragma unroll
            for (int rf = 0; rf < 4; ++rf) {
                const short8 af = *(const short8*)(As + (wr * 64 + rf * 16 + lrow) * 72 + kb);
                acc[rf][0] = __builtin_amdgcn_mfma_f32_16x16x32_bf16(af, bf0, acc[rf][0], 0, 0, 0);
                acc[rf][1] = __builtin_amdgcn_mfma_f32_16x16x32_bf16(af, bf1, acc[rf][1], 0, 0, 0);
            }
        }
        __syncthreads();
    }

    #pragma unroll
    for (int cf = 0; cf < 2; ++cf) {
        const int col = wcid * 32 + cf * 16 + lrow;
        const float bcv = bc[t * C_DIM + col];
        #pragma unroll
        for (int rf = 0; rf < 4; ++rf) {
            const int lr = wr * 64 + rf * 16 + (lane >> 4) * 4;
            #pragma unroll
            for (int r = 0; r < 4; ++r)
                out[(size_t)rows_s[lr + r] * C_DIM + col] = acc[rf][cf][r] + bcv;
        }
    }
}

extern "C" void kernel_launch(void* const* d_in, const int* in_sizes, int n_in,
                              void* d_out, int out_size, void* d_ws, size_t ws_size,
                              hipStream_t stream) {
    const float* x    = (const float*)d_in[0];
    const float* Wp   = (const float*)d_in[1];
    const float* bp   = (const float*)d_in[2];
    const float* sigs = (const float*)d_in[3];
    const float* Wc   = (const float*)d_in[4];
    const float* bc   = (const float*)d_in[5];
    float* out = (float*)d_out;
    char* ws = (char*)d_ws;

    hipMemsetAsync(ws + CNT_OFF, 0, 64, stream);
    prep_kernel<<<dim3(1601), dim3(256), 0, stream>>>(Wp, bp, sigs, Wc, ws);
    gemm_score_kernel<<<dim3(B_ROWS / BM), dim3(256), 0, stream>>>(x, bp, ws, out);
    logits_kernel<<<dim3(16 * 256), dim3(256), 0, stream>>>(bc, ws, out);
}

// Round 4
// 235.751 us; speedup vs baseline: 1.8667x; 1.2022x over previous
//
#include <hip/hip_runtime.h>

typedef short short8 __attribute__((ext_vector_type(8)));
typedef float f32x4 __attribute__((ext_vector_type(4)));

#define B_ROWS 32768
#define DIN 784
#define D_DIM 256
#define T_TILES 16
#define C_DIM 64
#define BM 64
#define NCHUNK 25   // ceil(784/32)

// ---- ws layout (bytes) ----
#define WPT_OFF    0u          // bf16 [25][256][32]  = 409600
#define WCT_OFF    409600u     // bf16 [16][64][256]  = 524288
#define WS_OFF     933888u     // f64  [800][16]      = 102400 (rows 784..799 zeroed)
#define BS_OFF     1036288u    // f64  [16]
#define H_OFF      1036416u    // bf16 [32768][256]   = 16777216
#define BUCKET_OFF 17813632u   // i32  [16][32768]    = 2097152
#define CNT_OFF    19910784u   // i32  [16]

static __device__ inline unsigned short f2bf(float f) {
    unsigned u = __builtin_bit_cast(unsigned, f);
    u += 0x7fffu + ((u >> 16) & 1u);          // RNE
    return (unsigned short)(u >> 16);
}
static __device__ inline double qtern(float s) {
    double v = (double)s;
    return (v > 0.3) ? 1.0 : ((v < -0.3) ? -1.0 : 0.0);
}

// ================= prep: WpT chunks (bf16), WcT (bf16), Ws/bs (f64), cnt=0 ==
__global__ __launch_bounds__(256)
void prep_kernel(const float* __restrict__ Wp, const float* __restrict__ bp,
                 const float* __restrict__ sigs_raw, const float* __restrict__ Wc,
                 char* __restrict__ ws) {
    __shared__ __align__(16) char u2[34816];
    const int bid = blockIdx.x, tid = threadIdx.x;
    unsigned short* wpt = (unsigned short*)(ws + WPT_OFF);
    unsigned short* wct = (unsigned short*)(ws + WCT_OFF);
    double* Wsd = (double*)(ws + WS_OFF);
    double* bsd = (double*)(ws + BS_OFF);

    if (bid < 25) {
        // WpT chunk transpose: Wp[k0..k0+32)[256] -> wpt[chunk][col][k&31], coalesced out
        unsigned short (*lt)[40] = (unsigned short (*)[40])u2;    // [256][40]
        const int k0 = bid * 32;
        #pragma unroll
        for (int p = 0; p < 8; ++p) {
            const int k = p * 4 + (tid >> 6);
            const int c = (tid & 63) * 4;
            float4 v = make_float4(0.f, 0.f, 0.f, 0.f);
            if (k0 + k < DIN) v = *(const float4*)&Wp[(size_t)(k0 + k) * D_DIM + c];
            lt[c + 0][k] = f2bf(v.x); lt[c + 1][k] = f2bf(v.y);
            lt[c + 2][k] = f2bf(v.z); lt[c + 3][k] = f2bf(v.w);
        }
        __syncthreads();
        const float4* src = (const float4*)&lt[tid][0];
        float4* dst = (float4*)(wpt + bid * 8192 + tid * 32);
        dst[0] = src[0]; dst[1] = src[1]; dst[2] = src[2]; dst[3] = src[3];
    } else if (bid < 123) {
        // Ws[k0..k0+8)[16] in f64
        float* sigq = (float*)u2;               // [16][256]
        float* wp8  = (float*)(u2 + 16384);     // [8][256]
        const int k0 = (bid - 25) * 8;
        #pragma unroll
        for (int i = 0; i < 16; ++i) {
            const int idx = i * 256 + tid;
            sigq[idx] = (float)qtern(sigs_raw[idx]);
        }
        #pragma unroll
        for (int i = 0; i < 8; ++i)
            wp8[i * 256 + tid] = Wp[(size_t)(k0 + i) * D_DIM + tid];
        __syncthreads();
        const int kk = tid >> 5, t = (tid >> 1) & 15, half = tid & 1;
        double s = 0.0;
        const float* wr = &wp8[kk * 256 + half * 128];
        const float* sq = &sigq[t * 256 + half * 128];
        for (int d = 0; d < 128; ++d) s += (double)wr[d] * (double)sq[d];
        s += __shfl_xor(s, 1);
        if (half == 0) Wsd[(k0 + kk) * 16 + t] = s;
    } else if (bid < 139) {
        // WcT[t][c][d] bf16, coalesced out
        unsigned short (*lc)[264] = (unsigned short (*)[264])u2;  // [64][264]
        const int t = bid - 123;
        #pragma unroll
        for (int j = 0; j < 16; ++j) {
            const int f4 = j * 256 + tid;
            const int d  = f4 >> 4;
            const int c4 = (f4 & 15) * 4;
            const float4 v = *(const float4*)&Wc[((size_t)t * D_DIM + d) * C_DIM + c4];
            lc[c4 + 0][d] = f2bf(v.x); lc[c4 + 1][d] = f2bf(v.y);
            lc[c4 + 2][d] = f2bf(v.z); lc[c4 + 3][d] = f2bf(v.w);
        }
        __syncthreads();
        const int c = tid >> 2, d0 = (tid & 3) * 64;
        const float4* src = (const float4*)&lc[c][d0];
        float4* dst = (float4*)(wct + t * 16384 + c * 256 + d0);
        #pragma unroll
        for (int i = 0; i < 8; ++i) dst[i] = src[i];
    } else {
        // bs[t] = bp @ sig_t ; zero Ws pad rows ; zero cnt
        int* cnt = (int*)(ws + CNT_OFF);
        if (tid < 16) cnt[tid] = 0;
        Wsd[12544 + tid] = 0.0;     // rows 784..799
        const int t = tid >> 4, l = tid & 15;
        double s = 0.0;
        #pragma unroll
        for (int j = 0; j < 16; ++j) {
            const int d = l * 16 + j;
            s += (double)bp[d] * qtern(sigs_raw[t * D_DIM + d]);
        }
        #pragma unroll
        for (int m = 8; m >= 1; m >>= 1) s += __shfl_xor(s, m);
        if (l == 0) bsd[t] = s;
    }
}

// ====== main: h = x@Wp+bp (bf16 MFMA) + fused f64 scores = x@Ws+bs ; bucket ==
__global__ __launch_bounds__(256, 2)
void gemm_score_kernel(const float* __restrict__ x, const float* __restrict__ bp,
                       char* __restrict__ ws, float* __restrict__ out) {
    __shared__ __align__(16) char u[59904];
    __shared__ int tidx_s[BM];

    unsigned short* Abuf = (unsigned short*)u;              // [2][64*40]
    unsigned short* Bbuf = (unsigned short*)(u + 10240);    // [2][256*40]
    double*         wss  = (double*)(u + 51200);            // [2][32*17]

    const unsigned short* wpt = (const unsigned short*)(ws + WPT_OFF);
    unsigned short* hbf = (unsigned short*)(ws + H_OFF);
    const double* Wsd = (const double*)(ws + WS_OFF);
    const double* bsd = (const double*)(ws + BS_OFF);
    int* bucket = (int*)(ws + BUCKET_OFF);
    int* cnt = (int*)(ws + CNT_OFF);

    const int tid = threadIdx.x;
    const int row0 = blockIdx.x * BM;
    const int wid = tid >> 6, lane = tid & 63;
    const int wr = wid >> 1, wcid = wid & 1;
    const int lrow = lane & 15, kb8 = (lane >> 4) * 8;
    const int ar = tid >> 2, ako = (tid & 3) * 8;           // A/score: row, k-offset
    const int wk = tid >> 3, wt = (tid * 2) & 15;           // Ws staging indices

    f32x4 acc[2][8];
    #pragma unroll
    for (int i = 0; i < 2; ++i)
        #pragma unroll
        for (int j = 0; j < 8; ++j) acc[i][j] = (f32x4){0.f, 0.f, 0.f, 0.f};
    double accd[16];
    #pragma unroll
    for (int t = 0; t < 16; ++t) accd[t] = 0.0;
    float xs8[8];

    // ---- prologue: stage chunk 0 ----
    {
        const float4* p = (const float4*)&x[(size_t)(row0 + ar) * DIN + ako];
        const float4 a0 = p[0], a1 = p[1];
        xs8[0] = a0.x; xs8[1] = a0.y; xs8[2] = a0.z; xs8[3] = a0.w;
        xs8[4] = a1.x; xs8[5] = a1.y; xs8[6] = a1.z; xs8[7] = a1.w;
        unsigned short tmp[8];
        #pragma unroll
        for (int i = 0; i < 8; ++i) tmp[i] = f2bf(xs8[i]);
        *(short8*)(Abuf + ar * 40 + ako) = *(short8*)tmp;
        const float4* q = (const float4*)(wpt + tid * 32);
        float4* db = (float4*)(Bbuf + tid * 40);
        db[0] = q[0]; db[1] = q[1]; db[2] = q[2]; db[3] = q[3];
        const double w0 = Wsd[tid * 2], w1 = Wsd[tid * 2 + 1];
        wss[wk * 17 + wt] = w0; wss[wk * 17 + wt + 1] = w1;
    }
    __syncthreads();

    for (int c = 0; c < NCHUNK; ++c) {
        const int cur = c & 1;
        const bool more = (c + 1 < NCHUNK);
        float4 va0, va1, vb0, vb1, vb2, vb3;
        double w0 = 0.0, w1 = 0.0;
        if (more) {
            const int kbase = (c + 1) * 32 + ako;
            if (kbase < DIN) {
                const float4* p = (const float4*)&x[(size_t)(row0 + ar) * DIN + kbase];
                va0 = p[0]; va1 = p[1];
            } else {
                va0 = make_float4(0, 0, 0, 0); va1 = make_float4(0, 0, 0, 0);
            }
            const float4* q = (const float4*)(wpt + (c + 1) * 8192 + tid * 32);
            vb0 = q[0]; vb1 = q[1]; vb2 = q[2]; vb3 = q[3];
            w0 = Wsd[(c + 1) * 512 + tid * 2];
            w1 = Wsd[(c + 1) * 512 + tid * 2 + 1];
        }
        // ---- MFMA chunk c ----
        {
            const unsigned short* Ab = Abuf + cur * 2560;
            const unsigned short* Bb = Bbuf + cur * 10240;
            const short8 af0 = *(const short8*)(Ab + (wr * 32 + lrow) * 40 + kb8);
            const short8 af1 = *(const short8*)(Ab + (wr * 32 + 16 + lrow) * 40 + kb8);
            #pragma unroll
            for (int cf = 0; cf < 8; ++cf) {
                const short8 bfr = *(const short8*)(Bb + (wcid * 128 + cf * 16 + lrow) * 40 + kb8);
                acc[0][cf] = __builtin_amdgcn_mfma_f32_16x16x32_bf16(af0, bfr, acc[0][cf], 0, 0, 0);
                acc[1][cf] = __builtin_amdgcn_mfma_f32_16x16x32_bf16(af1, bfr, acc[1][cf], 0, 0, 0);
            }
        }
        // ---- fused f64 score FMAs for chunk c (row ar, k = c*32+ako .. +8) ----
        {
            const double* wbase = wss + cur * 544;
            #pragma unroll
            for (int i = 0; i < 8; ++i) {
                const double xv = (double)xs8[i];
                const double* wrow = wbase + (ako + i) * 17;
                #pragma unroll
                for (int t = 0; t < 16; ++t) accd[t] += xv * wrow[t];
            }
        }
        if (more) {
            xs8[0] = va0.x; xs8[1] = va0.y; xs8[2] = va0.z; xs8[3] = va0.w;
            xs8[4] = va1.x; xs8[5] = va1.y; xs8[6] = va1.z; xs8[7] = va1.w;
            unsigned short tmp[8];
            #pragma unroll
            for (int i = 0; i < 8; ++i) tmp[i] = f2bf(xs8[i]);
            *(short8*)(Abuf + (cur ^ 1) * 2560 + ar * 40 + ako) = *(short8*)tmp;
            float4* db = (float4*)(Bbuf + (cur ^ 1) * 10240 + tid * 40);
            db[0] = vb0; db[1] = vb1; db[2] = vb2; db[3] = vb3;
            wss[(cur ^ 1) * 544 + wk * 17 + wt] = w0;
            wss[(cur ^ 1) * 544 + wk * 17 + wt + 1] = w1;
        }
        __syncthreads();
    }

    // ---- epilogue: h = acc + bp -> LDS (then coalesced global write) ----
    unsigned short* h_s = (unsigned short*)u;    // [64][264], aliases A/B bufs
    #pragma unroll
    for (int cf = 0; cf < 8; ++cf) {
        const int gc = wcid * 128 + cf * 16 + lrow;
        const float bpv = bp[gc];
        #pragma unroll
        for (int rf = 0; rf < 2; ++rf) {
            const int lr = wr * 32 + rf * 16 + (lane >> 4) * 4;
            #pragma unroll
            for (int r = 0; r < 4; ++r)
                h_s[(lr + r) * 264 + gc] = f2bf(acc[rf][cf][r] + bpv);
        }
    }

    // ---- score reduce (4 k-quarters per row) + argmax ----
    #pragma unroll
    for (int t = 0; t < 16; ++t) {
        accd[t] += __shfl_xor(accd[t], 1);
        accd[t] += __shfl_xor(accd[t], 2);
    }
    if ((tid & 3) == 0) {
        double best = -1.0e300; int bi = 0;
        #pragma unroll
        for (int t = 0; t < 16; ++t) {
            const double v = accd[t] + bsd[t];
            if (v > best) { best = v; bi = t; }
        }
        tidx_s[ar] = bi;
        out[(size_t)B_ROWS * C_DIM + row0 + ar] = (float)bi;
    }
    __syncthreads();

    // ---- coalesced h write: 64 shorts (8x float4) per thread ----
    {
        const int r = tid >> 2, q = tid & 3;
        const float4* src = (const float4*)(h_s + r * 264 + q * 64);
        float4 v[8];
        #pragma unroll
        for (int i = 0; i < 8; ++i) v[i] = src[i];
        float4* dst = (float4*)(hbf + (size_t)(row0 + r) * D_DIM + q * 64);
        #pragma unroll
        for (int i = 0; i < 8; ++i) dst[i] = v[i];
    }

    // ---- global bucketing ----
    if (tid < T_TILES) {
        int c = 0;
        for (int r = 0; r < BM; ++r) c += (tidx_s[r] == tid);
        int pos = atomicAdd(&cnt[tid], c);
        for (int r = 0; r < BM; ++r)
            if (tidx_s[r] == tid) bucket[tid * B_ROWS + (pos++)] = row0 + r;
    }
}

// ====== L: per-tile logits = h[rows] @ Wc[t] + bc[t] via MFMA ===============
__global__ __launch_bounds__(256)
void logits_kernel(const float* __restrict__ bc, const char* __restrict__ ws,
                   float* __restrict__ out) {
    __shared__ __align__(16) unsigned short As[128 * 136];
    __shared__ __align__(16) unsigned short Bs[64 * 136];
    __shared__ int rows_s[128];

    const int tid = threadIdx.x;
    const int t = blockIdx.x >> 8;
    const int c0 = (blockIdx.x & 255) * 128;
    const int* cnt = (const int*)(ws + CNT_OFF);
    const int cntv = cnt[t];
    if (c0 >= cntv) return;

    const int* bucket = (const int*)(ws + BUCKET_OFF);
    const unsigned short* hbf = (const unsigned short*)(ws + H_OFF);
    const unsigned short* wct = (const unsigned short*)(ws + WCT_OFF);

    if (tid < 128) {
        int i = c0 + tid; if (i >= cntv) i = cntv - 1;
        rows_s[tid] = bucket[t * B_ROWS + i];
    }
    __syncthreads();

    const int wid = tid >> 6, lane = tid & 63;
    const int wr = wid >> 1, wcid = wid & 1;
    const int lrow = lane & 15, kb8 = (lane >> 4) * 8;

    f32x4 acc[4][2];
    #pragma unroll
    for (int i = 0; i < 4; ++i) { acc[i][0] = (f32x4){0,0,0,0}; acc[i][1] = (f32x4){0,0,0,0}; }

    #pragma unroll
    for (int ch = 0; ch < 2; ++ch) {
        const int k0 = ch * 128;
        {
            // A: 128 rows x 128 k-shorts; 2 threads/row x 64 shorts (8x float4)
            const int r = tid >> 1, h64 = (tid & 1) * 64;
            const float4* p = (const float4*)(hbf + (size_t)rows_s[r] * D_DIM + k0 + h64);
            float4 v[8];
            #pragma unroll
            for (int i = 0; i < 8; ++i) v[i] = p[i];
            float4* d = (float4*)(As + r * 136 + h64);
            #pragma unroll
            for (int i = 0; i < 8; ++i) d[i] = v[i];
        }
        if (tid < 128) {
            // B: 64 cols x 128 k-shorts; 2 threads/col x 64 shorts (8x float4)
            const int c = tid >> 1, h64 = (tid & 1) * 64;
            const float4* p = (const float4*)(wct + (size_t)t * 16384 + c * 256 + k0 + h64);
            float4 v[8];
            #pragma unroll
            for (int i = 0; i < 8; ++i) v[i] = p[i];
            float4* d = (float4*)(Bs + c * 136 + h64);
            #pragma unroll
            for (int i = 0; i < 8; ++i) d[i] = v[i];
        }
        __syncthreads();
        #pragma unroll
        for (int ks = 0; ks < 4; ++ks) {
            const int kb = ks * 32 + kb8;
            const short8 bf0 = *(const short8*)(Bs + (wcid * 32 + lrow) * 136 + kb);
            const short8 bf1 = *(const short8*)(Bs + (wcid * 32 + 16 + lrow) * 136 + kb);
            #pragma unroll
            for (int rf = 0; rf < 4; ++rf) {
                const short8 af = *(const short8*)(As + (wr * 64 + rf * 16 + lrow) * 136 + kb);
                acc[rf][0] = __builtin_amdgcn_mfma_f32_16x16x32_bf16(af, bf0, acc[rf][0], 0, 0, 0);
                acc[rf][1] = __builtin_amdgcn_mfma_f32_16x16x32_bf16(af, bf1, acc[rf][1], 0, 0, 0);
            }
        }
        __syncthreads();
    }

    #pragma unroll
    for (int cf = 0; cf < 2; ++cf) {
        const int col = wcid * 32 + cf * 16 + lrow;
        const float bcv = bc[t * C_DIM + col];
        #pragma unroll
        for (int rf = 0; rf < 4; ++rf) {
            const int lr = wr * 64 + rf * 16 + (lane >> 4) * 4;
            #pragma unroll
            for (int r = 0; r < 4; ++r)
                out[(size_t)rows_s[lr + r] * C_DIM + col] = acc[rf][cf][r] + bcv;
        }
    }
}

extern "C" void kernel_launch(void* const* d_in, const int* in_sizes, int n_in,
                              void* d_out, int out_size, void* d_ws, size_t ws_size,
                              hipStream_t stream) {
    const float* x    = (const float*)d_in[0];
    const float* Wp   = (const float*)d_in[1];
    const float* bp   = (const float*)d_in[2];
    const float* sigs = (const float*)d_in[3];
    const float* Wc   = (const float*)d_in[4];
    const float* bc   = (const float*)d_in[5];
    float* out = (float*)d_out;
    char* ws = (char*)d_ws;

    prep_kernel<<<dim3(140), dim3(256), 0, stream>>>(Wp, bp, sigs, Wc, ws);
    gemm_score_kernel<<<dim3(B_ROWS / BM), dim3(256), 0, stream>>>(x, bp, ws, out);
    logits_kernel<<<dim3(16 * 256), dim3(256), 0, stream>>>(bc, ws, out);
}